// Round 5
// baseline (275.359 us; speedup 1.0000x reference)
//
#include <hip/hip_runtime.h>
#include <hip/hip_bf16.h>
#include <stdint.h>

// Problem constants
#define IN_DIM  512
#define OUT_DIM 512
#define BATCH   16384
#define BM      128
#define BN      256
#define BK      96               // 8 features * 12 slots = 3 mfma K-steps of 32
#define KCH     64               // 6144 / 96
#define TSTR    104              // A-tile padded row stride (bf16): 208B = 13 chunks
#define TILE    (256 * 96)       // elems per W2 (g,kc) tile, unpadded rows

typedef __bf16 bf16;
typedef __bf16 bf16x8 __attribute__((ext_vector_type(8)));
typedef float  f32x4  __attribute__((ext_vector_type(4)));

__device__ __forceinline__ uint bfbits(float v) {
    union { bf16 h; ushort u; } c; c.h = (bf16)v; return (uint)c.u;
}
__device__ __forceinline__ uint pk2(float lo, float hi) {
    return bfbits(lo) | (bfbits(hi) << 16);
}

// ---------------------------------------------------------------------------
// Pack W into B-fragment-ready tiles: W2[g*64+kc][r][c], r = n%256 (row-major,
// 96 cols unpadded). element (r,c) = coeff[n][i][k]*sspl (k<11) / sbase (k=11),
// i = kc*8 + c/12, k = c%12. One block per (g,kc) tile: dense 352B/row reads,
// perfectly linear 49KB writes.
// ---------------------------------------------------------------------------
__global__ void pack_w(const float* __restrict__ coeff,
                       const float* __restrict__ sbase,
                       const float* __restrict__ sspl,
                       bf16* __restrict__ W2) {
    const int b  = blockIdx.x;         // g*64 + kc
    const int g  = b >> 6, kc = b & 63;
    const int t  = threadIdx.x;        // row r = t
    const int o  = g * 256 + t;
    const float* cp = coeff + (size_t)o * (512 * 11) + kc * 88;   // 16B aligned
    float c[88];
#pragma unroll
    for (int j = 0; j < 22; ++j) *(float4*)(c + 4 * j) = *(const float4*)(cp + 4 * j);
    float ss[8], bb[8];
    *(float4*)(ss)     = *(const float4*)(sspl  + (size_t)o * 512 + kc * 8);
    *(float4*)(ss + 4) = *(const float4*)(sspl  + (size_t)o * 512 + kc * 8 + 4);
    *(float4*)(bb)     = *(const float4*)(sbase + (size_t)o * 512 + kc * 8);
    *(float4*)(bb + 4) = *(const float4*)(sbase + (size_t)o * 512 + kc * 8 + 4);
    union { bf16 hh[96]; uint4 uu[12]; } pk;
#pragma unroll
    for (int ic = 0; ic < 8; ++ic) {
#pragma unroll
        for (int k = 0; k < 11; ++k) pk.hh[ic * 12 + k] = (bf16)(c[ic * 11 + k] * ss[ic]);
        pk.hh[ic * 12 + 11] = (bf16)bb[ic];
    }
    uint4* dst = (uint4*)(W2 + ((size_t)b * 256 + t) * 96);
#pragma unroll
    for (int j = 0; j < 12; ++j) dst[j] = pk.uu[j];
}

// ---------------------------------------------------------------------------
// Fused KAN kernel. A (spline evals) through double-buffered LDS; B fragments
// loaded DIRECTLY global->VGPR (W2 row-major == MFMA B-frag layout), keeping
// the LDS pipe for A only. 512 thr = 8 waves (2m x 4n of 64x64), 1 block/CU.
// ---------------------------------------------------------------------------
__global__ void __launch_bounds__(512, 2) kan_gemm(
    const float* __restrict__ xg,
    const float* __restrict__ gridp,
    const float* __restrict__ bias,
    const bf16*  __restrict__ W2,
    float* __restrict__ out)
{
    __shared__ bf16 Abuf[2 * BM * TSTR];   // 53248 B total

    const int tid  = threadIdx.x;
    const int lane = tid & 63;
    const int wave = tid >> 6;
    const int g  = blockIdx.x;             // n-half; linear id % 8 keeps one g per XCD
    const int n0 = g * BN;
    const int m0 = blockIdx.y * BM;

    const float g0    = gridp[0];
    const float inv_h = 1.0f / (gridp[1] - gridp[0]);

    // MFMA wave layout
    const int wm = wave & 1, wn = wave >> 1;
    const int lr = lane & 15, lq = lane >> 4;

    // Per-lane B base: row (wn*64 + lr), col lq*8. Frag(nt,s,kc) at
    // + kc*TILE + nt*16*96 + s*32 elements.
    const bf16* Bw = W2 + (size_t)g * KCH * TILE + (wn * 64 + lr) * 96 + lq * 8;

    // Eval assignment: row = tid&127, feature pair fpair*2+{0,1}
    const int row_e = tid & 127;
    const int fpair = tid >> 7;            // 0..3
    const float* xrow = xg + (size_t)(m0 + row_e) * IN_DIM + fpair * 2;

    f32x4 acc[4][4];
#pragma unroll
    for (int mt = 0; mt < 4; ++mt)
#pragma unroll
        for (int nt = 0; nt < 4; ++nt) { f32x4 z = {0.f, 0.f, 0.f, 0.f}; acc[mt][nt] = z; }

    auto evalOne = [&](float xv, uint* De) {
        float f  = __builtin_fmaf(xv, inv_h, -g0 * inv_h);
        f = fminf(fmaxf(f, 7.0f), 14.9999f);
        float fj = floorf(f);
        int   j0 = (int)fj;
        float t  = f - fj;
        float t1 = t + 1.0f, t2 = t + 2.0f, t3 = t + 3.0f;
        float s1 = 1.0f - t, s2 = 2.0f - t, s3 = 3.0f - t, s4 = 4.0f - t;
        float a0 = 0.5f * t, a1 = 0.5f * s1;
        const float i3 = (1.0f / 3.0f);
        float b0 = t  * a0 * i3;
        float b1 = (t1 * a1 + s2 * a0) * i3;
        float b2 = s1 * a1 * i3;
        float c0 = t  * b0 * 0.25f;
        float c1 = (t1 * b1 + s3 * b0) * 0.25f;
        float c2 = (t2 * b2 + s2 * b1) * 0.25f;
        float c3 = s1 * b2 * 0.25f;
        float w0 = t  * c0 * 0.2f;
        float w1 = (t1 * c1 + s4 * c0) * 0.2f;
        float w2 = (t2 * c2 + s3 * c1) * 0.2f;
        float w3 = (t3 * c3 + s2 * c2) * 0.2f;
        float w4 = s1 * c3 * 0.2f;
        const int q0 = j0 - 4;             // [3,10]
        const int rr = q0 & 1;
        const int d  = q0 >> 1;            // [1,5]
        uint P0 = pk2(w4, w3), P1 = pk2(w2, w1), P2 = bfbits(w0);
        uint A0 = rr ? (P0 << 16)                : P0;
        uint A1 = rr ? ((P0 >> 16) | (P1 << 16)) : P1;
        uint A2 = rr ? ((P1 >> 16) | (P2 << 16)) : P2;
        De[0] = 0u;
        De[1] = (d == 1) ? A0 : 0u;
        De[2] = (d == 2) ? A0 : ((d == 1) ? A1 : 0u);
        De[3] = (d == 3) ? A0 : ((d == 2) ? A1 : ((d == 1) ? A2 : 0u));
        De[4] = (d == 4) ? A0 : ((d == 3) ? A1 : ((d == 2) ? A2 : 0u));
        uint D5 = (d == 5) ? A0 : ((d == 4) ? A1 : ((d == 3) ? A2 : 0u));
        De[5] = (D5 & 0xFFFFu) | (bfbits(xv + __sinf(xv)) << 16);
    };
    auto evalPair = [&](float2 xc, bf16* Adst) {
        uint D[12];
        evalOne(xc.x, D);
        evalOne(xc.y, D + 6);
        uint4* awr = (uint4*)(Adst + row_e * TSTR + fpair * 24);  // 48B, 16B-aligned
        awr[0] = make_uint4(D[0], D[1], D[2],  D[3]);
        awr[1] = make_uint4(D[4], D[5], D[6],  D[7]);
        awr[2] = make_uint4(D[8], D[9], D[10], D[11]);
    };

    // Prologue: x(0..1) regs, eval(0) -> Abuf[0]
    float2 xb0 = *(const float2*)(xrow);
    float2 xb1 = *(const float2*)(xrow + 8);
    evalPair(xb0, Abuf);
    xb0 = *(const float2*)(xrow + 16);     // x(2)
    __syncthreads();

    for (int kc = 0; kc < KCH; ++kc) {
        const int p = kc & 1;

        // B fragments for THIS chunk, direct global->VGPR (consumed pre-barrier,
        // so the barrier's vmcnt drain never waits on them cold)
        const bf16* Bk = Bw + (size_t)kc * TILE;
        bf16x8 bq[12];
#pragma unroll
        for (int s = 0; s < 3; ++s)
#pragma unroll
            for (int nt = 0; nt < 4; ++nt)
                bq[s * 4 + nt] = *(const bf16x8*)(Bk + nt * (16 * 96) + s * 32);

        // eval(kc+1) -> other A buffer while B loads are in flight
        if (kc < KCH - 1) {
            float2 xc = (kc & 1) ? xb0 : xb1;
            evalPair(xc, Abuf + (p ^ 1) * BM * TSTR);
            float2 xn = *(const float2*)(xrow + (((kc + 3) & (KCH - 1)) << 3));
            if (kc & 1) xb0 = xn; else xb1 = xn;
        }

        // MFMA on A buffer p + register B
        const bf16* Ap = Abuf + p * BM * TSTR;
#pragma unroll
        for (int s = 0; s < 3; ++s) {
            bf16x8 af[4];
#pragma unroll
            for (int mt = 0; mt < 4; ++mt)
                af[mt] = *(const bf16x8*)&Ap[(wm * 64 + mt * 16 + lr) * TSTR + s * 32 + lq * 8];
#pragma unroll
            for (int mt = 0; mt < 4; ++mt)
#pragma unroll
                for (int nt = 0; nt < 4; ++nt)
                    acc[mt][nt] = __builtin_amdgcn_mfma_f32_16x16x32_bf16(
                        af[mt], bq[s * 4 + nt], acc[mt][nt], 0, 0, 0);
        }
        __syncthreads();   // A buffer p free; p^1 eval-writes visible
    }

    // Epilogue: C/D layout col = lane&15, row = (lane>>4)*4 + reg
#pragma unroll
    for (int nt = 0; nt < 4; ++nt) {
        const int gcol = n0 + wn * 64 + nt * 16 + lr;
        const float bv = bias[gcol];
#pragma unroll
        for (int mt = 0; mt < 4; ++mt) {
#pragma unroll
            for (int i = 0; i < 4; ++i) {
                const int grow = m0 + wm * 64 + mt * 16 + lq * 4 + i;
                out[(size_t)grow * OUT_DIM + gcol] = acc[mt][nt][i] + bv;
            }
        }
    }
}

// ---------------------------------------------------------------------------
extern "C" void kernel_launch(void* const* d_in, const int* in_sizes, int n_in,
                              void* d_out, int out_size, void* d_ws, size_t ws_size,
                              hipStream_t stream) {
    const float* x     = (const float*)d_in[0];
    const float* gridv = (const float*)d_in[1];
    const float* coeff = (const float*)d_in[2];
    const float* sbase = (const float*)d_in[3];
    const float* sspl  = (const float*)d_in[4];
    const float* bias  = (const float*)d_in[5];
    float* out = (float*)d_out;
    bf16*  W2  = (bf16*)d_ws;   // 128 * 24576 * 2 = 6.29 MB workspace

    pack_w<<<dim3(128), 256, 0, stream>>>(coeff, sbase, sspl, W2);
    kan_gemm<<<dim3(OUT_DIM / BN, BATCH / BM), 512, 0, stream>>>(x, gridv, bias, W2, out);
}

// Round 7
// 244.430 us; speedup vs baseline: 1.1265x; 1.1265x over previous
//
#include <hip/hip_runtime.h>
#include <hip/hip_bf16.h>
#include <stdint.h>

// Problem constants
#define IN_DIM  512
#define OUT_DIM 512
#define BATCH   16384
#define BM      128
#define BN      256
#define BK      96               // 8 features * 12 slots = 3 mfma K-steps of 32
#define KCH     64               // 6144 / 96
#define TSTR    104              // A-tile padded row stride (bf16): 208B = 13 chunks
#define TILE    (256 * 96)       // elems per W2 (g,kc) tile, unpadded 96-col rows

typedef __bf16 bf16;
typedef __bf16 bf16x8 __attribute__((ext_vector_type(8)));
typedef float  f32x4  __attribute__((ext_vector_type(4)));

__device__ __forceinline__ uint bfbits(float v) {
    union { bf16 h; ushort u; } c; c.h = (bf16)v; return (uint)c.u;
}
__device__ __forceinline__ uint pk2(float lo, float hi) {
    return bfbits(lo) | (bfbits(hi) << 16);
}

// ---------------------------------------------------------------------------
// Pack W into B-fragment-ready tiles: W2[g*64+kc][r][c], r = n%256, 96 cols.
// element (r,c) = coeff[n][i][k]*sspl (k<11) / sbase (k=11), i = kc*8+c/12,
// k = c%12. 256 blocks: b = g*128 + kc*2 + mh; each stages 128 rows x 88
// coeff floats via LDS (linear float4 reads) and writes a linear 24.6 KB
// half-tile (thread u -> contiguous 96 B).
// ---------------------------------------------------------------------------
__global__ void pack_w(const float* __restrict__ coeff,
                       const float* __restrict__ sbase,
                       const float* __restrict__ sspl,
                       bf16* __restrict__ W2) {
    __shared__ float cs[128 * 88];         // 45056 B
    const int b  = blockIdx.x;             // 0..255
    const int g  = b >> 7;
    const int kc = (b >> 1) & 63;
    const int mh = b & 1;
    const int t  = threadIdx.x;
    const int o0 = g * 256 + mh * 128;     // first output row of this half-tile

    // Stage coeff[o0..o0+128)[kc*8..+8)[*] : 2816 float4, linear in both spaces
    const float4* c4 = (const float4*)coeff;   // coeff row = 1408 float4
    float4* cs4 = (float4*)cs;
#pragma unroll
    for (int j = 0; j < 11; ++j) {
        int idx = j * 256 + t;             // 0..2815
        int r   = idx / 22;                // row within slab
        int p   = idx - r * 22;            // float4 within row's 88 floats
        cs4[idx] = c4[(size_t)(o0 + r) * 1408 + kc * 22 + p];
    }
    __syncthreads();

    const int r = t >> 1, h = t & 1;       // row 0..127, col-half 0..1
    const int o = o0 + r;
    float4 ss = *(const float4*)(sspl  + (size_t)o * 512 + kc * 8 + h * 4);
    float4 bb = *(const float4*)(sbase + (size_t)o * 512 + kc * 8 + h * 4);
    const float* cp = cs + r * 88 + h * 44;
    union { bf16 hh[48]; uint4 uu[6]; } pk;
    const float s4[4] = {ss.x, ss.y, ss.z, ss.w};
    const float b4[4] = {bb.x, bb.y, bb.z, bb.w};
#pragma unroll
    for (int ic = 0; ic < 4; ++ic) {
#pragma unroll
        for (int k = 0; k < 11; ++k)
            pk.hh[ic * 12 + k] = (bf16)(cp[ic * 11 + k] * s4[ic]);
        pk.hh[ic * 12 + 11] = (bf16)b4[ic];
    }
    // FIX (r6 bug): tile row is mh*128 + r, not r — halves were overwriting.
    uint4* dst = (uint4*)(W2 + ((size_t)(g * 64 + kc) * 256 + mh * 128 + r) * 96 + h * 48);
#pragma unroll
    for (int j = 0; j < 6; ++j) dst[j] = pk.uu[j];
}

// ---------------------------------------------------------------------------
// Fused KAN kernel. A (spline evals) through double-buffered LDS; B fragments
// direct global->VGPR with ONE-ITERATION REGISTER PREFETCH (ping-pong q0/q1),
// so L2 latency+BW overlaps eval+MFMA instead of preceding it.
// 512 thr = 8 waves (2m x 4n of 64x64), 1 block/CU.
// ---------------------------------------------------------------------------
__global__ void __launch_bounds__(512, 2) kan_gemm(
    const float* __restrict__ xg,
    const float* __restrict__ gridp,
    const float* __restrict__ bias,
    const bf16*  __restrict__ W2,
    float* __restrict__ out)
{
    __shared__ bf16 Abuf[2 * BM * TSTR];   // 53248 B

    const int tid  = threadIdx.x;
    const int lane = tid & 63;
    const int wave = tid >> 6;
    const int g  = blockIdx.x;             // n-half; id%8 keeps one g per XCD
    const int n0 = g * BN;
    const int m0 = blockIdx.y * BM;

    const float g0    = gridp[0];
    const float inv_h = 1.0f / (gridp[1] - gridp[0]);

    // MFMA wave layout
    const int wm = wave & 1, wn = wave >> 1;
    const int lr = lane & 15, lq = lane >> 4;

    // Per-lane B base: row (wn*64 + lr), col lq*8.
    const bf16* Bw = W2 + (size_t)g * KCH * TILE + (wn * 64 + lr) * 96 + lq * 8;

    // Eval assignment: row = tid&127, feature pair fpair*2+{0,1}
    const int row_e = tid & 127;
    const int fpair = tid >> 7;            // 0..3
    const float* xrow = xg + (size_t)(m0 + row_e) * IN_DIM + fpair * 2;

    f32x4 acc[4][4];
#pragma unroll
    for (int mt = 0; mt < 4; ++mt)
#pragma unroll
        for (int nt = 0; nt < 4; ++nt) { f32x4 z = {0.f, 0.f, 0.f, 0.f}; acc[mt][nt] = z; }

    auto evalOne = [&](float xv, uint* De) {
        float f  = __builtin_fmaf(xv, inv_h, -g0 * inv_h);
        f = fminf(fmaxf(f, 7.0f), 14.9999f);
        float fj = floorf(f);
        int   j0 = (int)fj;
        float t  = f - fj;
        float t1 = t + 1.0f, t2 = t + 2.0f, t3 = t + 3.0f;
        float s1 = 1.0f - t, s2 = 2.0f - t, s3 = 3.0f - t, s4 = 4.0f - t;
        float a0 = 0.5f * t, a1 = 0.5f * s1;
        const float i3 = (1.0f / 3.0f);
        float b0 = t  * a0 * i3;
        float b1 = (t1 * a1 + s2 * a0) * i3;
        float b2 = s1 * a1 * i3;
        float c0 = t  * b0 * 0.25f;
        float c1 = (t1 * b1 + s3 * b0) * 0.25f;
        float c2 = (t2 * b2 + s2 * b1) * 0.25f;
        float c3 = s1 * b2 * 0.25f;
        float w0 = t  * c0 * 0.2f;
        float w1 = (t1 * c1 + s4 * c0) * 0.2f;
        float w2 = (t2 * c2 + s3 * c1) * 0.2f;
        float w3 = (t3 * c3 + s2 * c2) * 0.2f;
        float w4 = s1 * c3 * 0.2f;
        const int q0 = j0 - 4;             // [3,10]
        const int rr = q0 & 1;
        const int d  = q0 >> 1;            // [1,5]
        uint P0 = pk2(w4, w3), P1 = pk2(w2, w1), P2 = bfbits(w0);
        uint A0 = rr ? (P0 << 16)                : P0;
        uint A1 = rr ? ((P0 >> 16) | (P1 << 16)) : P1;
        uint A2 = rr ? ((P1 >> 16) | (P2 << 16)) : P2;
        De[0] = 0u;
        De[1] = (d == 1) ? A0 : 0u;
        De[2] = (d == 2) ? A0 : ((d == 1) ? A1 : 0u);
        De[3] = (d == 3) ? A0 : ((d == 2) ? A1 : ((d == 1) ? A2 : 0u));
        De[4] = (d == 4) ? A0 : ((d == 3) ? A1 : ((d == 2) ? A2 : 0u));
        uint D5 = (d == 5) ? A0 : ((d == 4) ? A1 : ((d == 3) ? A2 : 0u));
        De[5] = (D5 & 0xFFFFu) | (bfbits(xv + __sinf(xv)) << 16);
    };
    float2 xb0, xb1;
    auto evalPair = [&](float2 xc, bf16* Adst) {
        uint D[12];
        evalOne(xc.x, D);
        evalOne(xc.y, D + 6);
        uint4* awr = (uint4*)(Adst + row_e * TSTR + fpair * 24);  // 48B, 16B-aligned
        awr[0] = make_uint4(D[0], D[1], D[2],  D[3]);
        awr[1] = make_uint4(D[4], D[5], D[6],  D[7]);
        awr[2] = make_uint4(D[8], D[9], D[10], D[11]);
    };
    auto loadB = [&](int kc, bf16x8* q) {
        const bf16* Bk = Bw + (size_t)kc * TILE;
#pragma unroll
        for (int s = 0; s < 3; ++s)
#pragma unroll
            for (int nt = 0; nt < 4; ++nt)
                q[s * 4 + nt] = *(const bf16x8*)(Bk + nt * (16 * 96) + s * 32);
    };
    // eval(kc+1) into buffer (kc+1)&1; roll x prefetch regs (2 iters deep)
    auto evalNext = [&](int kc) {
        if (kc < KCH - 1) {
            float2 xc = (kc & 1) ? xb0 : xb1;
            evalPair(xc, Abuf + ((kc + 1) & 1) * BM * TSTR);
            float2 xn = *(const float2*)(xrow + (((kc + 3) & (KCH - 1)) << 3));
            if (kc & 1) xb0 = xn; else xb1 = xn;
        }
    };
    auto mfmaStep = [&](const bf16x8* q, int p) {
        const bf16* Ap = Abuf + p * BM * TSTR;
#pragma unroll
        for (int s = 0; s < 3; ++s) {
            bf16x8 af[4];
#pragma unroll
            for (int mt = 0; mt < 4; ++mt)
                af[mt] = *(const bf16x8*)&Ap[(wm * 64 + mt * 16 + lr) * TSTR + s * 32 + lq * 8];
#pragma unroll
            for (int mt = 0; mt < 4; ++mt)
#pragma unroll
                for (int nt = 0; nt < 4; ++nt)
                    acc[mt][nt] = __builtin_amdgcn_mfma_f32_16x16x32_bf16(
                        af[mt], q[s * 4 + nt], acc[mt][nt], 0, 0, 0);
        }
    };

    // Prologue: B(0) -> q0, x(0..1) -> regs, eval(0) -> Abuf[0]
    bf16x8 q0[12], q1[12];
    loadB(0, q0);
    xb0 = *(const float2*)(xrow);
    xb1 = *(const float2*)(xrow + 8);
    evalPair(xb0, Abuf);
    xb0 = *(const float2*)(xrow + 16);     // x(2)
    __syncthreads();

    for (int kc = 0; kc < KCH; kc += 2) {
        // ---- even half: consume q0/buf0, prefetch B(kc+1) -> q1 ----
        loadB(kc + 1, q1);                 // in flight across eval + MFMA
        evalNext(kc);                      // eval(kc+1) -> Abuf[1]
        mfmaStep(q0, 0);
        __syncthreads();
        // ---- odd half: consume q1/buf1, prefetch B(kc+2) -> q0 ----
        if (kc + 2 < KCH) loadB(kc + 2, q0);
        evalNext(kc + 1);                  // eval(kc+2) -> Abuf[0]
        mfmaStep(q1, 1);
        __syncthreads();
    }

    // Epilogue: C/D layout col = lane&15, row = (lane>>4)*4 + reg
#pragma unroll
    for (int nt = 0; nt < 4; ++nt) {
        const int gcol = n0 + wn * 64 + nt * 16 + lr;
        const float bv = bias[gcol];
#pragma unroll
        for (int mt = 0; mt < 4; ++mt) {
#pragma unroll
            for (int i = 0; i < 4; ++i) {
                const int grow = m0 + wm * 64 + mt * 16 + lq * 4 + i;
                out[(size_t)grow * OUT_DIM + gcol] = acc[mt][nt][i] + bv;
            }
        }
    }
}

// ---------------------------------------------------------------------------
extern "C" void kernel_launch(void* const* d_in, const int* in_sizes, int n_in,
                              void* d_out, int out_size, void* d_ws, size_t ws_size,
                              hipStream_t stream) {
    const float* x     = (const float*)d_in[0];
    const float* gridv = (const float*)d_in[1];
    const float* coeff = (const float*)d_in[2];
    const float* sbase = (const float*)d_in[3];
    const float* sspl  = (const float*)d_in[4];
    const float* bias  = (const float*)d_in[5];
    float* out = (float*)d_out;
    bf16*  W2  = (bf16*)d_ws;   // 128 * 24576 * 2 = 6.29 MB workspace

    pack_w<<<dim3(256), 256, 0, stream>>>(coeff, sbase, sspl, W2);
    kan_gemm<<<dim3(OUT_DIM / BN, BATCH / BM), 512, 0, stream>>>(x, gridv, bias, W2, out);
}